// Round 6
// baseline (930.203 us; speedup 1.0000x reference)
//
#include <hip/hip_runtime.h>
#include <math.h>

#define N_NODES 50000
#define N_EDGES 1600000
#define DIM_IN  128
#define DIM_HID 64
#define NHEADS  8
#define HDIM    (NHEADS*DIM_HID)   // 512
#define DIM_OUT 128
#define SMBLK   1024               // blocks for scatter+max1 pass
#define MAXBLK  512                // blocks for max2 pass
#define LDK     72                 // padded LDS row (bf16 elems)
#define AGG1_NB 12500              // node-blocks per segment (4 nodes/block)

typedef __attribute__((ext_vector_type(2))) unsigned short us2;
typedef __attribute__((ext_vector_type(4))) unsigned short us4;
typedef __attribute__((ext_vector_type(8))) unsigned short us8;
typedef __attribute__((ext_vector_type(8))) short bf16x8;
typedef __attribute__((ext_vector_type(4))) float f32x4;

__device__ __forceinline__ float leaky(float x) { return x >= 0.f ? x : 0.2f * x; }
__device__ __forceinline__ float bf2f(unsigned short h) {
  return __uint_as_float(((unsigned)h) << 16);
}
__device__ __forceinline__ unsigned short f2bf(float f) {
  unsigned u = __float_as_uint(f);
  unsigned r = (u + 0x7fffu + ((u >> 16) & 1u)) >> 16;
  return (unsigned short)r;
}

// ---------- fused prep: cvt feat->bf16 | pack W_heads | pack W_res ----------
__global__ void prep_kernel(const float* __restrict__ feat, const float* __restrict__ Wh,
                            const float* __restrict__ Wres,
                            unsigned short* __restrict__ feat_bf,
                            unsigned short* __restrict__ Bt1,
                            unsigned short* __restrict__ Btr) {
  int b = blockIdx.x;
  if (b < 6250) {
    int i = b * 256 + threadIdx.x;
    float4 v = *reinterpret_cast<const float4*>(&feat[(size_t)i * 4]);
    us4 o;
    o[0] = f2bf(v.x); o[1] = f2bf(v.y); o[2] = f2bf(v.z); o[3] = f2bf(v.w);
    *reinterpret_cast<us4*>(&feat_bf[(size_t)i * 4]) = o;
  } else if (b < 6506) {
    int idx = (b - 6250) * 256 + threadIdx.x;
    int n = idx >> 7, k = idx & 127;
    Bt1[idx] = f2bf(Wh[(n >> 6) * (DIM_IN * DIM_HID) + k * DIM_HID + (n & 63)]);
  } else {
    int idx = (b - 6506) * 256 + threadIdx.x;
    int n = idx >> 7, k = idx & 127;
    Btr[idx] = f2bf(Wres[k * DIM_OUT + n]);
  }
}

// ---------- fold BN1 scale into W_out -> Bt2 [128][512] bf16 ----------
__global__ void foldw2_kernel(const float* __restrict__ W, const float* __restrict__ scale,
                              unsigned short* __restrict__ Bt) {
  int idx = blockIdx.x * 256 + threadIdx.x;
  if (idx >= DIM_OUT * HDIM) return;
  int n = idx >> 9, k = idx & 511;
  Bt[idx] = f2bf(W[k * DIM_OUT + n] * scale[k]);
}

// ---------- bf16 MFMA GEMM: C[M,N] = A[M,K] @ Bt[N,K]^T (+bias) ----------
template<int OUTBF>
__global__ __launch_bounds__(256) void gemm_mfma(
    const unsigned short* __restrict__ A, const unsigned short* __restrict__ Bt,
    void* __restrict__ Cout, const float* __restrict__ bias,
    int M, int N, int K) {
  __shared__ unsigned short As[128 * LDK];
  __shared__ unsigned short Bs[128 * LDK];
  const int tid = threadIdx.x;
  const int lane = tid & 63, wid = tid >> 6;
  const int wr = wid >> 1, wc = wid & 1;
  const int l15 = lane & 15, lhi = lane >> 4;
  const int m0 = blockIdx.y * 128, n0 = blockIdx.x * 128;
  const int srow = tid >> 3;
  const int sc8 = (tid - srow) & 7;
  f32x4 acc[4][4];
#pragma unroll
  for (int i = 0; i < 4; ++i)
#pragma unroll
    for (int j = 0; j < 4; ++j) acc[i][j] = f32x4{0.f, 0.f, 0.f, 0.f};

  for (int k0 = 0; k0 < K; k0 += 64) {
    __syncthreads();
#pragma unroll
    for (int p = 0; p < 4; ++p) {
      int row = p * 32 + srow;
      us8 va = {0, 0, 0, 0, 0, 0, 0, 0};
      int gr = m0 + row;
      if (gr < M) va = *reinterpret_cast<const us8*>(&A[(size_t)gr * K + k0 + sc8 * 8]);
      *reinterpret_cast<us8*>(&As[row * LDK + sc8 * 8]) = va;
      us8 vb = {0, 0, 0, 0, 0, 0, 0, 0};
      int gn = n0 + row;
      if (gn < N) vb = *reinterpret_cast<const us8*>(&Bt[(size_t)gn * K + k0 + sc8 * 8]);
      *reinterpret_cast<us8*>(&Bs[row * LDK + sc8 * 8]) = vb;
    }
    __syncthreads();
#pragma unroll
    for (int kk = 0; kk < 2; ++kk) {
      bf16x8 af[4], bfr[4];
#pragma unroll
      for (int i = 0; i < 4; ++i)
        af[i] = *reinterpret_cast<const bf16x8*>(&As[(wr * 64 + i * 16 + l15) * LDK + kk * 32 + lhi * 8]);
#pragma unroll
      for (int j = 0; j < 4; ++j)
        bfr[j] = *reinterpret_cast<const bf16x8*>(&Bs[(wc * 64 + j * 16 + l15) * LDK + kk * 32 + lhi * 8]);
#pragma unroll
      for (int i = 0; i < 4; ++i)
#pragma unroll
        for (int j = 0; j < 4; ++j)
          acc[i][j] = __builtin_amdgcn_mfma_f32_16x16x32_bf16(af[i], bfr[j], acc[i][j], 0, 0, 0);
    }
  }
#pragma unroll
  for (int j = 0; j < 4; ++j) {
    int col = n0 + wc * 64 + j * 16 + l15;
    float bb = bias ? bias[col] : 0.f;
#pragma unroll
    for (int i = 0; i < 4; ++i) {
      f32x4 v = acc[i][j];
#pragma unroll
      for (int t = 0; t < 4; ++t) {
        int row = m0 + wr * 64 + i * 16 + lhi * 4 + t;
        if (row < M) {
          float o = v[t] + bb;
          if (OUTBF) ((unsigned short*)Cout)[(size_t)row * N + col] = f2bf(o);
          else       ((float*)Cout)[(size_t)row * N + col] = o;
        }
      }
    }
  }
}

// ---------- attn projections layer 1 (bf16 msg) ----------
__global__ __launch_bounds__(256) void attn1_kernel(
    const unsigned short* __restrict__ msg, const float* __restrict__ a_heads,
    float* __restrict__ asrc, float* __restrict__ adst, int Nn) {
  int lane = threadIdx.x & 63;
  int n = blockIdx.x * 4 + (threadIdx.x >> 6);
  if (n >= Nn) return;
  us8 v = *reinterpret_cast<const us8*>(&msg[(size_t)n * HDIM + lane * 8]);
  int h = lane >> 3, p0 = (lane & 7) * 8;
  float s = 0.f, d = 0.f;
#pragma unroll
  for (int j = 0; j < 8; ++j) {
    float f = bf2f(v[j]);
    s = fmaf(f, a_heads[h * 128 + p0 + j], s);
    d = fmaf(f, a_heads[h * 128 + 64 + p0 + j], d);
  }
  s += __shfl_xor(s, 1, 64); s += __shfl_xor(s, 2, 64); s += __shfl_xor(s, 4, 64);
  d += __shfl_xor(d, 1, 64); d += __shfl_xor(d, 2, 64); d += __shfl_xor(d, 4, 64);
  if ((lane & 7) == 0) { asrc[n * 8 + h] = s; adst[n * 8 + h] = d; }
}

// ---------- attn projections layer 2 (bf16 msg) ----------
__global__ __launch_bounds__(256) void attn2_kernel(
    const unsigned short* __restrict__ msg, const float* __restrict__ a_out,
    float* __restrict__ asrc, float* __restrict__ adst, int Nn) {
  int lane = threadIdx.x & 63;
  int n = blockIdx.x * 4 + (threadIdx.x >> 6);
  if (n >= Nn) return;
  us2 v = *reinterpret_cast<const us2*>(&msg[(size_t)n * 128 + lane * 2]);
  float f0 = bf2f(v[0]), f1 = bf2f(v[1]);
  float s = f0 * a_out[2 * lane] + f1 * a_out[2 * lane + 1];
  float d = f0 * a_out[128 + 2 * lane] + f1 * a_out[128 + 2 * lane + 1];
#pragma unroll
  for (int off = 32; off; off >>= 1) {
    s += __shfl_xor(s, off, 64);
    d += __shfl_xor(d, off, 64);
  }
  if (lane == 0) { asrc[n] = s; adst[n] = d; }
}

// ---------- CSR: histogram ----------
__global__ void hist_kernel(const int* __restrict__ edst, int* __restrict__ counts, int E) {
  for (int e = blockIdx.x * blockDim.x + threadIdx.x; e < E; e += gridDim.x * blockDim.x)
    atomicAdd(&counts[edst[e]], 1);
}

// ---------- CSR: 3-phase scan ----------
__global__ __launch_bounds__(256) void scan1_kernel(
    const int* __restrict__ counts, int* __restrict__ rowptr, int* __restrict__ bsum, int n) {
  __shared__ int wsum[4];
  int b0 = blockIdx.x * 1024;
  int t = threadIdx.x;
  int lane = t & 63, w = t >> 6;
  int v[4]; int s = 0;
#pragma unroll
  for (int i = 0; i < 4; ++i) {
    int idx = b0 + t * 4 + i;
    v[i] = (idx < n) ? counts[idx] : 0;
    s += v[i];
  }
  int x = s;
#pragma unroll
  for (int off = 1; off < 64; off <<= 1) {
    int y = __shfl_up(x, off, 64);
    if (lane >= off) x += y;
  }
  if (lane == 63) wsum[w] = x;
  __syncthreads();
  int wof = 0;
  for (int i = 0; i < w; ++i) wof += wsum[i];
  int run = wof + x - s;
#pragma unroll
  for (int i = 0; i < 4; ++i) {
    int idx = b0 + t * 4 + i;
    if (idx < n) rowptr[idx] = run;
    run += v[i];
  }
  if (t == 255) bsum[blockIdx.x] = wof + x;
}

__global__ void scan2_kernel(int* __restrict__ bsum, int nb) {
  int t = threadIdx.x;
  int v = (t < nb) ? bsum[t] : 0;
  int x = v;
#pragma unroll
  for (int off = 1; off < 64; off <<= 1) {
    int y = __shfl_up(x, off, 64);
    if (t >= off) x += y;
  }
  if (t < nb) bsum[t] = x - v;
}

__global__ void scan3_kernel(int* __restrict__ rowptr, const int* __restrict__ bsum, int n) {
  int i = blockIdx.x * 256 + threadIdx.x;
  if (i < n) rowptr[i] += bsum[i >> 10];
  else if (i == n) rowptr[n] = N_EDGES;
}

// ---------- fused scatter + layer-1 max partials ----------
__global__ __launch_bounds__(256) void scatter_max1_kernel(
    const int* __restrict__ esrc, const int* __restrict__ edst,
    const float* __restrict__ asrc, const float* __restrict__ adst,
    const int* __restrict__ rowptr, int* __restrict__ cursor,
    int* __restrict__ colsrc, float* __restrict__ part, int E) {
  float m[8];
#pragma unroll
  for (int h = 0; h < 8; ++h) m[h] = -3.4e38f;
  for (int e = blockIdx.x * blockDim.x + threadIdx.x; e < E; e += gridDim.x * blockDim.x) {
    int s = esrc[e], d = edst[e];
    int pos = rowptr[d] + atomicAdd(&cursor[d], 1);
    colsrc[pos] = s;
    float4 s0 = *reinterpret_cast<const float4*>(&asrc[(size_t)s * 8]);
    float4 s1 = *reinterpret_cast<const float4*>(&asrc[(size_t)s * 8 + 4]);
    float4 d0 = *reinterpret_cast<const float4*>(&adst[(size_t)d * 8]);
    float4 d1 = *reinterpret_cast<const float4*>(&adst[(size_t)d * 8 + 4]);
    float xs[8] = {s0.x + d0.x, s0.y + d0.y, s0.z + d0.z, s0.w + d0.w,
                   s1.x + d1.x, s1.y + d1.y, s1.z + d1.z, s1.w + d1.w};
#pragma unroll
    for (int h = 0; h < 8; ++h) m[h] = fmaxf(m[h], leaky(xs[h]));
  }
#pragma unroll
  for (int h = 0; h < 8; ++h)
#pragma unroll
    for (int off = 32; off; off >>= 1) m[h] = fmaxf(m[h], __shfl_xor(m[h], off, 64));
  __shared__ float sm[4][8];
  int wv = threadIdx.x >> 6, ln = threadIdx.x & 63;
  if (ln == 0)
#pragma unroll
    for (int h = 0; h < 8; ++h) sm[wv][h] = m[h];
  __syncthreads();
  if (threadIdx.x < 8) {
    int h = threadIdx.x;
    part[blockIdx.x * 8 + h] =
        fmaxf(fmaxf(sm[0][h], sm[1][h]), fmaxf(sm[2][h], sm[3][h]));
  }
}

__global__ void max1_final_kernel(const float* __restrict__ part, float* __restrict__ maxv, int nblk) {
  int t = threadIdx.x;
  int h = t & 7, k = t >> 3;
  float m = -3.4e38f;
  for (int i = k; i < nblk; i += 8) m = fmaxf(m, part[i * 8 + h]);
  m = fmaxf(m, __shfl_xor(m, 8, 64));
  m = fmaxf(m, __shfl_xor(m, 16, 64));
  m = fmaxf(m, __shfl_xor(m, 32, 64));
  if (t < 8) maxv[t] = m;
}

// ---------- layer-2 max, two-stage ----------
__global__ __launch_bounds__(256) void max2_part_kernel(
    const int* __restrict__ esrc, const int* __restrict__ edst,
    const float* __restrict__ asrc, const float* __restrict__ adst,
    float* __restrict__ part, int E) {
  float m = -3.4e38f;
  for (int e = blockIdx.x * blockDim.x + threadIdx.x; e < E; e += gridDim.x * blockDim.x) {
    float x = asrc[esrc[e]] + adst[edst[e]];
    m = fmaxf(m, leaky(x));
  }
#pragma unroll
  for (int off = 32; off; off >>= 1) m = fmaxf(m, __shfl_xor(m, off, 64));
  __shared__ float sm[4];
  int wv = threadIdx.x >> 6, ln = threadIdx.x & 63;
  if (ln == 0) sm[wv] = m;
  __syncthreads();
  if (threadIdx.x == 0)
    part[blockIdx.x] = fmaxf(fmaxf(sm[0], sm[1]), fmaxf(sm[2], sm[3]));
}

__global__ void max2_final_kernel(const float* __restrict__ part, float* __restrict__ maxv, int nblk) {
  int t = threadIdx.x;
  float m = -3.4e38f;
  for (int i = t; i < nblk; i += 64) m = fmaxf(m, part[i]);
#pragma unroll
  for (int off = 32; off; off >>= 1) m = fmaxf(m, __shfl_xor(m, off, 64));
  if (t == 0) maxv[0] = m;
}

// ---------- layer-1 aggregation: 4 segments x 2 heads, wave-per-node, barrier-free ----------
// blockIdx [0,12500) seg0, [12500,25000) seg1, ... segment-major for L2 locality:
// active gather table per segment = 12.8 MB (cols 128*seg..128*seg+128 of msg).
__global__ __launch_bounds__(256) void agg1_kernel(
    const unsigned short* __restrict__ msg, const float* __restrict__ asrc,
    const float* __restrict__ adst, const float* __restrict__ maxv,
    const int* __restrict__ rowptr, const int* __restrict__ colsrc,
    unsigned short* __restrict__ out) {
  int seg = blockIdx.x / AGG1_NB;
  int nb  = blockIdx.x - seg * AGG1_NB;
  int wv = threadIdx.x >> 6, ln = threadIdx.x & 63;
  int n = nb * 4 + wv;
  int h = seg * 2 + (ln >> 5);                 // this lane's head
  int colbase = h * 64 + (ln & 31) * 2;        // bf16 column in msg/out row
  float M = maxv[h];
  float ad = adst[(size_t)n * 8 + h];
  int e0 = rowptr[n], e1 = rowptr[n + 1];
  float acc0 = 0.f, acc1 = 0.f, ds = 0.f;
  int e = e0;
  for (; e + 4 <= e1; e += 4) {
    int4 ss = *reinterpret_cast<const int4*>(&colsrc[e]);   // wave-broadcast 16B
    float x0 = asrc[(size_t)ss.x * 8 + h] + ad;
    float x1 = asrc[(size_t)ss.y * 8 + h] + ad;
    float x2 = asrc[(size_t)ss.z * 8 + h] + ad;
    float x3 = asrc[(size_t)ss.w * 8 + h] + ad;
    us2 m0 = *reinterpret_cast<const us2*>(&msg[(size_t)ss.x * HDIM + colbase]);
    us2 m1 = *reinterpret_cast<const us2*>(&msg[(size_t)ss.y * HDIM + colbase]);
    us2 m2 = *reinterpret_cast<const us2*>(&msg[(size_t)ss.z * HDIM + colbase]);
    us2 m3 = *reinterpret_cast<const us2*>(&msg[(size_t)ss.w * HDIM + colbase]);
    x0 = x0 >= 0.f ? x0 : 0.2f * x0;  float c0 = __expf(x0 - M);
    x1 = x1 >= 0.f ? x1 : 0.2f * x1;  float c1 = __expf(x1 - M);
    x2 = x2 >= 0.f ? x2 : 0.2f * x2;  float c2 = __expf(x2 - M);
    x3 = x3 >= 0.f ? x3 : 0.2f * x3;  float c3 = __expf(x3 - M);
    ds += (c0 + c1) + (c2 + c3);
    acc0 = fmaf(bf2f(m0[0]), c0, acc0); acc1 = fmaf(bf2f(m0[1]), c0, acc1);
    acc0 = fmaf(bf2f(m1[0]), c1, acc0); acc1 = fmaf(bf2f(m1[1]), c1, acc1);
    acc0 = fmaf(bf2f(m2[0]), c2, acc0); acc1 = fmaf(bf2f(m2[1]), c2, acc1);
    acc0 = fmaf(bf2f(m3[0]), c3, acc0); acc1 = fmaf(bf2f(m3[1]), c3, acc1);
  }
  for (; e < e1; ++e) {
    int s = colsrc[e];
    float x = asrc[(size_t)s * 8 + h] + ad;
    us2 m = *reinterpret_cast<const us2*>(&msg[(size_t)s * HDIM + colbase]);
    x = x >= 0.f ? x : 0.2f * x;
    float c = __expf(x - M);
    ds += c;
    acc0 = fmaf(bf2f(m[0]), c, acc0);
    acc1 = fmaf(bf2f(m[1]), c, acc1);
  }
  float inv = 1.0f / (ds + 1e-10f);
  us2 o;
  o[0] = f2bf(acc0 * inv);
  o[1] = f2bf(acc1 * inv);
  *reinterpret_cast<us2*>(&out[(size_t)n * HDIM + colbase]) = o;
}

// ---------- layer-2 aggregation: wave-per-node, shfl-broadcast coefs, unroll 4 ----------
__global__ __launch_bounds__(256) void agg2_kernel(
    const unsigned short* __restrict__ msg, const float* __restrict__ asrc,
    const float* __restrict__ adst, const float* __restrict__ maxv,
    const int* __restrict__ rowptr, const int* __restrict__ colsrc,
    float* __restrict__ out) {
  int wv = threadIdx.x >> 6, ln = threadIdx.x & 63;
  int n = blockIdx.x * 4 + wv;
  float M = maxv[0];
  float ad = adst[n];
  int e0 = rowptr[n], e1 = rowptr[n + 1];
  float a0 = 0.f, a1 = 0.f, ds = 0.f;
  for (int base = e0; base < e1; base += 64) {
    int cnt = min(64, e1 - base);
    int s_reg = 0; float c_reg = 0.f;
    if (ln < cnt) {
      s_reg = colsrc[base + ln];
      float x = asrc[s_reg] + ad;
      x = x >= 0.f ? x : 0.2f * x;
      c_reg = __expf(x - M);
    }
    int e = 0;
    for (; e + 4 <= cnt; e += 4) {
      int s0 = __shfl(s_reg, e, 64),     s1 = __shfl(s_reg, e + 1, 64);
      int s2 = __shfl(s_reg, e + 2, 64), s3 = __shfl(s_reg, e + 3, 64);
      float c0 = __shfl(c_reg, e, 64),     c1 = __shfl(c_reg, e + 1, 64);
      float c2 = __shfl(c_reg, e + 2, 64), c3 = __shfl(c_reg, e + 3, 64);
      us2 m0 = *reinterpret_cast<const us2*>(&msg[(size_t)s0 * 128 + 2 * ln]);
      us2 m1 = *reinterpret_cast<const us2*>(&msg[(size_t)s1 * 128 + 2 * ln]);
      us2 m2 = *reinterpret_cast<const us2*>(&msg[(size_t)s2 * 128 + 2 * ln]);
      us2 m3 = *reinterpret_cast<const us2*>(&msg[(size_t)s3 * 128 + 2 * ln]);
      ds += (c0 + c1) + (c2 + c3);
      a0 = fmaf(bf2f(m0[0]), c0, a0); a1 = fmaf(bf2f(m0[1]), c0, a1);
      a0 = fmaf(bf2f(m1[0]), c1, a0); a1 = fmaf(bf2f(m1[1]), c1, a1);
      a0 = fmaf(bf2f(m2[0]), c2, a0); a1 = fmaf(bf2f(m2[1]), c2, a1);
      a0 = fmaf(bf2f(m3[0]), c3, a0); a1 = fmaf(bf2f(m3[1]), c3, a1);
    }
    for (; e < cnt; ++e) {
      int s = __shfl(s_reg, e, 64);
      float c = __shfl(c_reg, e, 64);
      us2 m = *reinterpret_cast<const us2*>(&msg[(size_t)s * 128 + 2 * ln]);
      ds += c;
      a0 = fmaf(bf2f(m[0]), c, a0);
      a1 = fmaf(bf2f(m[1]), c, a1);
    }
  }
  float inv = 1.0f / (ds + 1e-10f);
  float2 r; r.x = a0 * inv; r.y = a1 * inv;
  *reinterpret_cast<float2*>(&out[(size_t)n * 128 + 2 * ln]) = r;
}

// ---------- BN statistics ----------
__global__ void colstats_kernel(const float* __restrict__ X, float* __restrict__ sums,
                                float* __restrict__ sqs, int M, int C, int rowsPerBlock) {
  int c = blockIdx.x * blockDim.x + threadIdx.x;
  if (c >= C) return;
  int r0 = blockIdx.y * rowsPerBlock;
  int r1 = min(M, r0 + rowsPerBlock);
  float s = 0.f, s2 = 0.f;
  for (int r = r0; r < r1; ++r) {
    float v = X[(size_t)r * C + c];
    s += v; s2 = fmaf(v, v, s2);
  }
  atomicAdd(&sums[c], s);
  atomicAdd(&sqs[c], s2);
}

__global__ void colstats_bf_kernel(const unsigned short* __restrict__ X, float* __restrict__ sums,
                                   float* __restrict__ sqs, int M, int C, int rowsPerBlock) {
  int c = blockIdx.x * blockDim.x + threadIdx.x;
  if (c >= C) return;
  int r0 = blockIdx.y * rowsPerBlock;
  int r1 = min(M, r0 + rowsPerBlock);
  float s = 0.f, s2 = 0.f;
  for (int r = r0; r < r1; ++r) {
    float v = bf2f(X[(size_t)r * C + c]);
    s += v; s2 = fmaf(v, v, s2);
  }
  atomicAdd(&sums[c], s);
  atomicAdd(&sqs[c], s2);
}

__global__ void bnparams_kernel(const float* __restrict__ sums, const float* __restrict__ sqs,
                                const float* __restrict__ gamma, const float* __restrict__ beta,
                                float* __restrict__ scale, float* __restrict__ shift,
                                int C, float invM) {
  int c = blockIdx.x * blockDim.x + threadIdx.x;
  if (c >= C) return;
  float mean = sums[c] * invM;
  float var = sqs[c] * invM - mean * mean;
  float inv = rsqrtf(var + 1e-5f);
  float sc = gamma[c] * inv;
  scale[c] = sc;
  shift[c] = beta[c] - mean * sc;
}

__global__ void bias2_kernel(const float* __restrict__ W, const float* __restrict__ shift,
                             float* __restrict__ bias2) {
  int j = threadIdx.x;
  if (j >= DIM_OUT) return;
  float s = 0.f;
  for (int c = 0; c < HDIM; ++c) s = fmaf(shift[c], W[c * DIM_OUT + j], s);
  bias2[j] = s;
}

// ---------- final: BN(out2) + residual ----------
__global__ void final_kernel(float* __restrict__ out, const float* __restrict__ resid,
                             const float* __restrict__ scale, const float* __restrict__ shift,
                             int total) {
  for (int i = blockIdx.x * blockDim.x + threadIdx.x; i < total; i += gridDim.x * blockDim.x) {
    int c = i & 127;
    out[i] = fmaf(out[i], scale[c], shift[c]) + resid[i];
  }
}

// ==================== host ====================
extern "C" void kernel_launch(void* const* d_in, const int* in_sizes, int n_in,
                              void* d_out, int out_size, void* d_ws, size_t ws_size,
                              hipStream_t stream) {
  const float* feat    = (const float*)d_in[0];
  const int*   edges   = (const int*)d_in[1];
  const int*   esrc    = edges;
  const int*   edst    = edges + N_EDGES;
  const float* W_heads = (const float*)d_in[2];
  const float* a_heads = (const float*)d_in[3];
  const float* gamma_h = (const float*)d_in[4];
  const float* beta_h  = (const float*)d_in[5];
  const float* W_out   = (const float*)d_in[6];
  const float* a_out   = (const float*)d_in[7];
  const float* gamma_o = (const float*)d_in[8];
  const float* beta_o  = (const float*)d_in[9];
  const float* W_res   = (const float*)d_in[10];
  const float* b_res   = (const float*)d_in[11];
  float* out = (float*)d_out;

  char* ws = (char*)d_ws;
  size_t off = 0;
  auto alloc = [&](size_t bytes) {
    void* p = ws + off;
    off = (off + bytes + 255) & ~(size_t)255;
    return p;
  };
  unsigned short* msg1    = (unsigned short*)alloc((size_t)N_NODES * HDIM * 2);  // reused as msg2
  unsigned short* out1_bf = (unsigned short*)alloc((size_t)N_NODES * HDIM * 2);
  unsigned short* feat_bf = (unsigned short*)alloc((size_t)N_NODES * DIM_IN * 2);
  float*    resid  = (float*)alloc((size_t)N_NODES * DIM_OUT * 4);
  float*    asrc1  = (float*)alloc((size_t)N_NODES * NHEADS * 4); // reused as asrc2
  float*    adst1  = (float*)alloc((size_t)N_NODES * NHEADS * 4); // reused as adst2
  int*      counts = (int*)alloc((size_t)N_NODES * 4);
  int*      cursor = (int*)alloc((size_t)N_NODES * 4);   // adjacent to counts
  int*      rowptr = (int*)alloc((size_t)(N_NODES + 1) * 4);
  int*      colsrc = (int*)alloc((size_t)N_EDGES * 4);
  int*      bsum   = (int*)alloc(64 * 4);
  float*    part   = (float*)alloc((size_t)SMBLK * 8 * 4);
  float*    maxv1  = (float*)alloc(8 * 4);
  float*    maxv2  = (float*)alloc(4);
  float*    colsum = (float*)alloc(HDIM * 4);
  float*    colsq  = (float*)alloc(HDIM * 4);   // adjacent to colsum
  float*    scale1 = (float*)alloc(HDIM * 4);
  float*    shift1 = (float*)alloc(HDIM * 4);
  float*    scale2 = (float*)alloc(DIM_OUT * 4);
  float*    shift2 = (float*)alloc(DIM_OUT * 4);
  unsigned short* Bt1 = (unsigned short*)alloc((size_t)HDIM * DIM_IN * 2);
  unsigned short* Bt2 = (unsigned short*)alloc((size_t)DIM_OUT * HDIM * 2);
  unsigned short* Btr = (unsigned short*)alloc((size_t)DIM_OUT * DIM_IN * 2);
  float*    bias2  = (float*)alloc(DIM_OUT * 4);
  unsigned short* msg2 = msg1;
  float* asrc2 = asrc1; float* adst2 = adst1;
  (void)n_in; (void)in_sizes; (void)out_size; (void)ws_size;

  // merged zero-init: counts+cursor contiguous; colsum+colsq contiguous
  hipMemsetAsync(counts, 0, (char*)rowptr - (char*)counts, stream);
  hipMemsetAsync(colsum, 0, (char*)scale1 - (char*)colsum, stream);

  // ---- prep (cvt + packs fused) ----
  prep_kernel<<<6570, 256, 0, stream>>>(feat, W_heads, W_res, feat_bf, Bt1, Btr);

  // ---- layer 1 ----
  dim3 g1(HDIM / 128, (N_NODES + 127) / 128);
  gemm_mfma<1><<<g1, 256, 0, stream>>>(feat_bf, Bt1, msg1, nullptr, N_NODES, HDIM, DIM_IN);
  attn1_kernel<<<(N_NODES + 3) / 4, 256, 0, stream>>>(msg1, a_heads, asrc1, adst1, N_NODES);

  hist_kernel<<<2048, 256, 0, stream>>>(edst, counts, N_EDGES);
  int nsb = (N_NODES + 1023) / 1024;   // 49
  scan1_kernel<<<nsb, 256, 0, stream>>>(counts, rowptr, bsum, N_NODES);
  scan2_kernel<<<1, 64, 0, stream>>>(bsum, nsb);
  scan3_kernel<<<(N_NODES + 256) / 256, 256, 0, stream>>>(rowptr, bsum, N_NODES);

  scatter_max1_kernel<<<SMBLK, 256, 0, stream>>>(esrc, edst, asrc1, adst1, rowptr,
                                                 cursor, colsrc, part, N_EDGES);
  max1_final_kernel<<<1, 64, 0, stream>>>(part, maxv1, SMBLK);
  agg1_kernel<<<4 * AGG1_NB, 256, 0, stream>>>(msg1, asrc1, adst1, maxv1, rowptr, colsrc, out1_bf);

  colstats_bf_kernel<<<dim3(HDIM / 128, 98), 128, 0, stream>>>(out1_bf, colsum, colsq, N_NODES, HDIM, 512);
  bnparams_kernel<<<(HDIM + 127) / 128, 128, 0, stream>>>(colsum, colsq, gamma_h, beta_h,
                                                          scale1, shift1, HDIM, 1.0f / N_NODES);
  foldw2_kernel<<<(DIM_OUT * HDIM + 255) / 256, 256, 0, stream>>>(W_out, scale1, Bt2);
  bias2_kernel<<<1, 128, 0, stream>>>(W_out, shift1, bias2);

  // ---- layer 2 ----
  dim3 g2(DIM_OUT / 128, (N_NODES + 127) / 128);
  gemm_mfma<1><<<g2, 256, 0, stream>>>(out1_bf, Bt2, msg2, bias2, N_NODES, DIM_OUT, HDIM);
  attn2_kernel<<<(N_NODES + 3) / 4, 256, 0, stream>>>(msg2, a_out, asrc2, adst2, N_NODES);

  max2_part_kernel<<<MAXBLK, 256, 0, stream>>>(esrc, edst, asrc2, adst2, part, N_EDGES);
  max2_final_kernel<<<1, 64, 0, stream>>>(part, maxv2, MAXBLK);
  agg2_kernel<<<N_NODES / 4, 256, 0, stream>>>(msg2, asrc2, adst2, maxv2, rowptr, colsrc, out);

  // residual GEMM (bf16 MFMA, fp32 out)
  gemm_mfma<0><<<g2, 256, 0, stream>>>(feat_bf, Btr, resid, b_res, N_NODES, DIM_OUT, DIM_IN);

  // layer-2 BN + residual
  hipMemsetAsync(colsum, 0, (char*)scale1 - (char*)colsum, stream);
  colstats_kernel<<<dim3(1, 98), 128, 0, stream>>>(out, colsum, colsq, N_NODES, DIM_OUT, 512);
  bnparams_kernel<<<1, 128, 0, stream>>>(colsum, colsq, gamma_o, beta_o,
                                         scale2, shift2, DIM_OUT, 1.0f / N_NODES);
  final_kernel<<<2048, 256, 0, stream>>>(out, resid, scale2, shift2, N_NODES * DIM_OUT);
}